// Round 1
// baseline (28.100 us; speedup 1.0000x reference)
//
#include <hip/hip_runtime.h>

// SillyEmbedding: out[n, d] = sum_k coef[k] * basis[k, ids[n], d]
//   ids:   (B*S,)           int32,  N = 8192
//   coef:  (K=16,)          float32
//   basis: (K, V=32000, D=256) float32   (k-stride = V*D floats)
//   out:   (N, D)           float32
//
// Pure gather, memory-bound: ~134 MB basis reads + 8 MB writes.
// Block = 256 threads = 4 tokens x 64 float4-lanes (16 B/lane, coalesced).

#define SE_V 32000
#define SE_D 256
#define SE_K 16

__global__ __launch_bounds__(256)
void silly_embedding_kernel(const int* __restrict__ ids,
                            const float* __restrict__ coef,
                            const float4* __restrict__ basis,
                            float4* __restrict__ out,
                            int n_tokens) {
    __shared__ float s_coef[SE_K];
    if (threadIdx.x < SE_K) s_coef[threadIdx.x] = coef[threadIdx.x];
    __syncthreads();

    const int tok = blockIdx.x * 4 + (threadIdx.x >> 6);   // 4 tokens / block
    const int d4  = threadIdx.x & 63;                      // float4 index in D
    if (tok >= n_tokens) return;

    const int id = ids[tok];
    const float4* __restrict__ p = basis + (size_t)id * (SE_D / 4) + d4;
    const size_t kstride = (size_t)SE_V * (SE_D / 4);      // float4 stride per k-plane

    float4 acc = make_float4(0.f, 0.f, 0.f, 0.f);
    #pragma unroll
    for (int k = 0; k < SE_K; ++k) {
        const float4 v = p[(size_t)k * kstride];
        const float  c = s_coef[k];
        acc.x += c * v.x;
        acc.y += c * v.y;
        acc.z += c * v.z;
        acc.w += c * v.w;
    }
    out[(size_t)tok * (SE_D / 4) + d4] = acc;
}

extern "C" void kernel_launch(void* const* d_in, const int* in_sizes, int n_in,
                              void* d_out, int out_size, void* d_ws, size_t ws_size,
                              hipStream_t stream) {
    const int*    ids   = (const int*)d_in[0];
    const float*  coef  = (const float*)d_in[1];
    const float4* basis = (const float4*)d_in[2];
    float4*       out   = (float4*)d_out;

    const int n_tokens = in_sizes[0];                 // B*S = 8192
    const int blocks   = (n_tokens + 3) / 4;          // 4 tokens per block

    silly_embedding_kernel<<<blocks, 256, 0, stream>>>(ids, coef, basis, out, n_tokens);
}

// Round 4
// 27.391 us; speedup vs baseline: 1.0259x; 1.0259x over previous
//
#include <hip/hip_runtime.h>

// SillyEmbedding: out[n, d] = sum_k coef[k] * basis[k, ids[n], d]
//   ids:   (B*S=8192,)      int32
//   coef:  (K=16,)          float32
//   basis: (K, V=32000, D=256) float32
//   out:   (N, D)           float32
//
// Memory-bound gather: ~116 MB unique HBM reads + 8.4 MB writes -> ~20 us floor.
// Per wave: one token, 64 lanes x float4 = 1 KB coalesced per k-plane.
// id is wave-uniform -> readfirstlane forces scalar-base addressing.
//
// NOTE: no nontemporal store — nt bypasses the write-back L2 while the
// harness's poison fill leaves dirty lines there; post-timing readback then
// sees stale poison (R2 post-mortem). Plain global_store is coherent.

#define SE_V 32000
#define SE_D 256
#define SE_K 16

typedef float f32x4 __attribute__((ext_vector_type(4)));

__global__ __launch_bounds__(256)
void silly_embedding_kernel(const int* __restrict__ ids,
                            const float* __restrict__ coef,
                            const float* __restrict__ basis,
                            float* __restrict__ out,
                            int n_tokens) {
    const int tok  = blockIdx.x * 4 + (threadIdx.x >> 6);   // 4 tokens / block (1 per wave)
    const int lane = threadIdx.x & 63;
    if (tok >= n_tokens) return;

    // Wave-uniform id -> scalar register; gather addresses become s[base] + lane*16.
    const int id = __builtin_amdgcn_readfirstlane(ids[tok]);

    const float* __restrict__ p = basis + (size_t)id * SE_D + (size_t)lane * 4;
    const size_t kstride = (size_t)SE_V * SE_D;   // floats per k-plane

    f32x4 acc = (f32x4){0.f, 0.f, 0.f, 0.f};
    #pragma unroll
    for (int k = 0; k < SE_K; ++k) {
        const f32x4 v = *reinterpret_cast<const f32x4*>(p + (size_t)k * kstride);
        const float c = coef[k];                  // thread-uniform -> s_load
        acc = v * c + acc;                        // vector fma
    }

    *(reinterpret_cast<f32x4*>(out + (size_t)tok * SE_D) + lane) = acc;
}

extern "C" void kernel_launch(void* const* d_in, const int* in_sizes, int n_in,
                              void* d_out, int out_size, void* d_ws, size_t ws_size,
                              hipStream_t stream) {
    const int*   ids   = (const int*)d_in[0];
    const float* coef  = (const float*)d_in[1];
    const float* basis = (const float*)d_in[2];
    float*       out   = (float*)d_out;

    const int n_tokens = in_sizes[0];            // B*S = 8192
    const int blocks   = (n_tokens + 3) / 4;     // 4 tokens per block

    silly_embedding_kernel<<<blocks, 256, 0, stream>>>(ids, coef, basis, out, n_tokens);
}